// Round 19
// baseline (275.757 us; speedup 1.0000x reference)
//
#include <hip/hip_runtime.h>
#include <hip/hip_bf16.h>

typedef __attribute__((ext_vector_type(8))) short short8;
typedef __attribute__((ext_vector_type(4))) float f32x4;
typedef __attribute__((ext_vector_type(16))) float f32x16;

static __device__ __forceinline__ f32x4 MFMA16(short8 a, short8 b, f32x4 c) {
    return __builtin_amdgcn_mfma_f32_16x16x32_bf16(a, b, c, 0, 0, 0);
}
static __device__ __forceinline__ f32x16 MFMA32(short8 a, short8 b, f32x16 c) {
    return __builtin_amdgcn_mfma_f32_32x32x16_bf16(a, b, c, 0, 0, 0);
}
static __device__ __forceinline__ unsigned short f2bf(float f) {
    union { __hip_bfloat16 h; unsigned short u; } c;
    c.h = __float2bfloat16(f);
    return c.u;
}
static __device__ __forceinline__ void gload16(const void* g, void* l) {
    __builtin_amdgcn_global_load_lds(
        (const __attribute__((address_space(1))) unsigned int*)g,
        (__attribute__((address_space(3))) unsigned int*)l, 16, 0, 0);
}

// ---------------- ws layout ----------------
// wst  : bf16, LDS-order pre-swizzled w_in, PER-HEAD: [12 h][6 s][768 gran x16B] @0 (884736)
// wos  : bf16, LDS-order pre-swizzled w_out [3 nb][6 s][1024 gran x16B] @ 884736 (294912)
// brr  : f32  [12][96] head-major bias                                  @ 1179648 (4608)
// attst: bf16, pre-swizzled att [1024 mb][6 s][16384 B]                 @ 1184256 (100663296)
// xbf  : bf16 fragment-ordered x [1024 mb][6 s][8 f][2 c][64 lanes x16B] -> lives in d_out
constexpr size_t kWstOff = 0;
constexpr size_t kWosOff = 884736;
constexpr size_t kBrrOff = 1179648;
constexpr size_t kAttOff = 1184256;

// ================= kernel 0: prep (convert + reorder weights) =================
__global__ void prep(const float* __restrict__ w_in, const float* __restrict__ b_in,
                     const float* __restrict__ w_out,
                     char* __restrict__ wst, char* __restrict__ wos,
                     float* __restrict__ brr)
{
    const int i = blockIdx.x * 256 + threadIdx.x;   // grid covers 73728 exactly
    if (i < 55296) {
        int h = i / 4608, rem = i % 4608;
        int s = rem / 768, t = rem % 768;
        int row = t >> 3, sl = t & 7;
        int c8 = sl ^ (row & 7);
        int sec = row >> 5, d = row & 31;
        int srow = sec * 384 + h * 32 + d;
        int k0 = s * 64 + c8 * 8;
        const float4* src = (const float4*)(w_in + (size_t)srow * 384 + k0);
        float4 a = src[0], b = src[1];
        uint4 w;
        w.x = f2bf(a.x) | ((unsigned)f2bf(a.y) << 16);
        w.y = f2bf(a.z) | ((unsigned)f2bf(a.w) << 16);
        w.z = f2bf(b.x) | ((unsigned)f2bf(b.y) << 16);
        w.w = f2bf(b.z) | ((unsigned)f2bf(b.w) << 16);
        *(uint4*)(wst + (size_t)i * 16) = w;
    } else {
        int j = i - 55296;                           // [0, 18432)
        int nb = j / 6144, rem = j % 6144;
        int s = rem / 1024, slot16 = rem % 1024;
        int row = slot16 >> 3, sl = slot16 & 7;
        int c8 = sl ^ (row & 7);
        int srow = nb * 128 + row;
        int k0 = s * 64 + c8 * 8;
        const float4* src = (const float4*)(w_out + (size_t)srow * 384 + k0);
        float4 a = src[0], b = src[1];
        uint4 w;
        w.x = f2bf(a.x) | ((unsigned)f2bf(a.y) << 16);
        w.y = f2bf(a.z) | ((unsigned)f2bf(a.w) << 16);
        w.z = f2bf(b.x) | ((unsigned)f2bf(b.y) << 16);
        w.w = f2bf(b.z) | ((unsigned)f2bf(b.w) << 16);
        *(uint4*)(wos + (size_t)j * 16) = w;
    }
    if (i < 1152) {
        int h = i / 96, jj = i % 96;
        int sec = jj >> 5, d = jj & 31;
        brr[i] = b_in[sec * 384 + h * 32 + d];
    }
}

// ================= kernel 0b: prep_x — x (f32) -> MFMA-fragment-ordered bf16 ====
__global__ void prep_x(const float* __restrict__ x, char* __restrict__ xbf)
{
    const int i = blockIdx.x * 256 + threadIdx.x;    // grid covers 6291456 exactly
    const int lane = i & 63;
    const int cc = (i >> 6) & 1;
    const int f = (i >> 7) & 7;
    const int rem = i >> 10;                          // mb*6 + s
    const int s = rem % 6, mb = rem / 6;

    int T = mb * 128 + f * 16 + (lane & 15);
    int win = T >> 4, t4 = T & 15;
    int bb = win >> 8, wh = (win >> 4) & 15, ww = win & 15;
    int n = (wh * 4 + (t4 >> 2)) * 64 + ww * 4 + (t4 & 3);
    int k0 = s * 64 + cc * 32 + (lane >> 4) * 8;

    const float4* src = (const float4*)(x + ((size_t)bb * 4096 + n) * 384 + k0);
    float4 a = src[0], b = src[1];
    uint4 w;
    w.x = f2bf(a.x) | ((unsigned)f2bf(a.y) << 16);
    w.y = f2bf(a.z) | ((unsigned)f2bf(a.w) << 16);
    w.z = f2bf(b.x) | ((unsigned)f2bf(b.y) << 16);
    w.w = f2bf(b.z) | ((unsigned)f2bf(b.w) << 16);
    *(uint4*)(xbf + (size_t)i * 16) = w;
}

// ================= kernel A: QKV projection + window attention =================
// grid: 1024 m-blocks x 12 heads = 12288. block = 256 thr (4 waves).
// BM=128, BN=96, BK=64. Wave = M32 x N96 via mfma_32x32x16 -> acc = 3 x f32x16.
// 2x MFMA work per B LDS byte vs 16x16 (LDS pipe was the saturated resource).
// A: 4 fragment loads/step from xbf (global). B: counted-vmcnt triple-buffer DMA.
// Tail tiles per window: Q,K in [t][64B] slot-swizzled (1 b128 gather each);
// V in [d][t] (uint2 path). Tiles @0..24576 alias B bufs 0/1; step5 reads buf 2.
__global__ __launch_bounds__(256, 4)
void qkv_attn(const char* __restrict__ xbf, const char* __restrict__ wst,
              const float* __restrict__ brr, char* __restrict__ attst)
{
    __shared__ __align__(16) char smem[36864];

    const int tid  = threadIdx.x;
    const int lane = tid & 63, wid = tid >> 6;         // 4 waves = 4 M32-frags
    const int g = lane >> 4, r16 = lane & 15;
    const int l31 = lane & 31, lh = lane >> 5;

    // head-fastest grouping within each XCD (L2: 8 xbf slices + 12 W slices)
    int b = blockIdx.x;
    int x8 = b & 7, j = b >> 3;                        // j 0..1535
    const int head = j % 12;
    const int mblk = x8 * 128 + j / 12;                // 0..1023

    // A base: lane row = wid*32 + l31 -> frag f = wid*2 + (l31>>4), r16' = l15
    const char* xwA = xbf + (size_t)mblk * 98304
                    + (size_t)(wid * 2 + ((lane >> 4) & 1)) * 2048 + (lane & 15) * 16;
    const char* whp = wst + (size_t)head * 73728;

    auto stage_B = [&](int s, int buf) {               // 768 granules, 3/thread
        char* dst = smem + buf * 12288 + tid * 16;
        const char* src = whp + s * 12288 + tid * 16;
        gload16(src, dst);
        gload16(src + 4096, dst + 4096);
        gload16(src + 8192, dst + 8192);
    };
    auto loadA = [&](int s, short8* a) {
        #pragma unroll
        for (int kk = 0; kk < 4; ++kk)
            a[kk] = *(const short8*)(xwA + s * 16384 + (kk >> 1) * 1024
                                     + ((kk & 1) * 2 + lh) * 256);
    };

    f32x16 acc[3] = {};
    short8 acur[4], anext[4];

    // prologue (oldest->newest): B0 DMA, A0 loads, B1 DMA
    stage_B(0, 0);
    loadA(0, acur);
    stage_B(1, 1);

    #pragma unroll
    for (int s = 0; s < 6; ++s) {
        // counted wait: A(s)+B(s) complete; keep newest 3 (B(s+1) DMA) in flight
        __builtin_amdgcn_sched_barrier(0);
        if (s < 5) { asm volatile("s_waitcnt vmcnt(3)" ::: "memory"); }
        else       { asm volatile("s_waitcnt vmcnt(0)" ::: "memory"); }
        __builtin_amdgcn_sched_barrier(0);
        __builtin_amdgcn_s_barrier();                  // raw: no compiler drain
        __builtin_amdgcn_sched_barrier(0);

        if (s < 5) loadA(s + 1, anext);
        __builtin_amdgcn_sched_barrier(0);             // pin DMA after A-loads
        if (s < 4) stage_B(s + 2, (s + 2) % 3);        // overwrites buf (s-1)%3

        const char* bbp = smem + (s % 3) * 12288;
        #pragma unroll
        for (int kk = 0; kk < 4; ++kk) {
            #pragma unroll
            for (int ni = 0; ni < 3; ++ni) {
                const int row = ni * 32 + l31;
                // global k-octet for this sub-step: c8' = kk*2 + lh  (FIX: was
                // (kk&1)*2+lh, which re-read octets 0-3 for kk=2,3)
                short8 bf = *(const short8*)(bbp + row * 128 +
                                (((kk * 2 + lh) ^ (row & 7)) << 4));
                acc[ni] = MFMA32(acur[kk], bf, acc[ni]);
            }
        }
        #pragma unroll
        for (int kk = 0; kk < 4; ++kk) acur[kk] = anext[kk];
    }
    // tail tiles @0..24576 (= B bufs 0/1) vs step-5 reads (buf 2 @24576): disjoint;
    // earlier-step reads closed by barrier(5). Tiles wave-private: NO barrier.

    // ---- epilogue: acc (+bias) -> tiles. C layout: col=l31, row=(reg&3)+8q+4lh ----
    // Q/K: [t][64B] with slot=(d>>3)^((t>>2)&3) swizzle; V: [d][t].
    char* wt0 = smem + (wid * 2) * 3072;
    char* wt1 = smem + (wid * 2 + 1) * 3072;
    #pragma unroll
    for (int ni = 0; ni < 3; ++ni) {
        const float bias = brr[head * 96 + ni * 32 + l31];
        #pragma unroll
        for (int q = 0; q < 4; ++q) {
            const int rbase = q * 8 + lh * 4;          // rows rbase..rbase+3
            char* tb = (q < 2) ? wt0 : wt1;            // rows<16 -> win even
            const int t0 = rbase & 15;
            if (ni < 2) {
                const int slot = (((l31 >> 3) ^ ((t0 >> 2) & 3)) << 4) + (l31 & 7) * 2;
                #pragma unroll
                for (int jj = 0; jj < 4; ++jj)
                    *(unsigned short*)(tb + ni * 1024 + (t0 + jj) * 64 + slot)
                        = f2bf(acc[ni][q * 4 + jj] + bias);
            } else {
                uint2 w;
                w.x = f2bf(acc[2][q * 4 + 0] + bias) |
                      ((unsigned)f2bf(acc[2][q * 4 + 1] + bias) << 16);
                w.y = f2bf(acc[2][q * 4 + 2] + bias) |
                      ((unsigned)f2bf(acc[2][q * 4 + 3] + bias) << 16);
                *(uint2*)(tb + 2048 + l31 * 32 + t0 * 2) = w;
            }
        }
    }

    // ---- attention: wave wid owns windows wid*2, wid*2+1 (same head) ----
    const float kC = 0.17677669529663687f * 1.4426950408889634f;  // (1/sqrt32)*log2e
    const f32x4 zero = {0.f, 0.f, 0.f, 0.f};
    const int qsl = ((g ^ ((r16 >> 2) & 3)) << 4);

    #pragma unroll
    for (int i = 0; i < 2; ++i) {
        const int win = wid * 2 + i;
        char* tile = smem + win * 3072;

        // Q/K fragment: ONE swizzle-clean b128 each: [t=r16][d=g*8..+7]
        short8 qv = *(const short8*)(tile + r16 * 64 + qsl);
        short8 kv = *(const short8*)(tile + 1024 + r16 * 64 + qsl);
        f32x4 s = MFMA16(kv, qv, zero);         // D[key=4g+r][q=r16]

        float m = fmaxf(fmaxf(s[0], s[1]), fmaxf(s[2], s[3]));
        m = fmaxf(m, __shfl_xor(m, 16, 64));
        m = fmaxf(m, __shfl_xor(m, 32, 64));
        float p[4], sum = 0.f;
        #pragma unroll
        for (int r = 0; r < 4; ++r) { p[r] = exp2f((s[r] - m) * kC); sum += p[r]; }
        sum += __shfl_xor(sum, 16, 64);
        sum += __shfl_xor(sum, 32, 64);
        const float inv = 1.f / sum;

        // P as in-register A-fragment under k-perm k=4g+j (upper 4 elems zero);
        // V's B-fragment uses the SAME key permutation.
        union U8 { unsigned short e[8]; short8 v; };
        U8 pu;
        pu.e[0] = f2bf(p[0] * inv); pu.e[1] = f2bf(p[1] * inv);
        pu.e[2] = f2bf(p[2] * inv); pu.e[3] = f2bf(p[3] * inv);
        pu.e[4] = 0; pu.e[5] = 0; pu.e[6] = 0; pu.e[7] = 0;

        f32x4 o[2];
        #pragma unroll
        for (int ti = 0; ti < 2; ++ti) {
            U8 vu;                               // V[key=4g+j][d=ti*16+r16]
            *(uint2*)&vu.e[0] = *(const uint2*)(tile + 2048 + (ti * 16 + r16) * 32 + g * 8);
            vu.e[4] = 0; vu.e[5] = 0; vu.e[6] = 0; vu.e[7] = 0;
            o[ti] = MFMA16(pu.v, vu.v, zero);    // D[q=4g+r][d-col=r16]
        }

        // transpose o via tile's (now dead) Q area -> [t][64B] rows, then
        // ONE uint4 global store per lane into attst's granule layout.
        #pragma unroll
        for (int ti = 0; ti < 2; ++ti)
            #pragma unroll
            for (int r = 0; r < 4; ++r)
                *(unsigned short*)(tile + (g * 4 + r) * 64 + (ti * 16 + r16) * 2)
                    = f2bf(o[ti][r]);
        uint4 ov = *(const uint4*)(tile + r16 * 64 + g * 16);  // same-wave RAW

        int row7 = win * 16 + r16;               // row within this mblk (BM=128)
        int col8 = head * 4 + g;                 // 16B-granule column index
        int sst = col8 >> 3;
        int sl = (col8 & 7) ^ (row7 & 7);
        *(uint4*)(attst + (size_t)mblk * 98304 + sst * 16384 + row7 * 128 + sl * 16) = ov;
    }
}

// ================= kernel B: out projection =================
// grid: 1024 m-blocks x 3 n-blocks = 3072. BM=128, BN=128, BK=64.
__global__ __launch_bounds__(256, 2)
void out_proj(const char* __restrict__ attst, const char* __restrict__ wos,
              const float* __restrict__ b_out, float* __restrict__ out)
{
    __shared__ __align__(16) char smem[65536];  // A 2x16K @0 ; B 2x16K @32768

    const int tid  = threadIdx.x;
    const int lane = tid & 63, wid = tid >> 6;
    const int g = lane >> 4, r16 = lane & 15;
    const int wm = wid >> 1, wn = wid & 1;

    int b = blockIdx.x;
    int L = (b & 7) * 384 + (b >> 3);
    const int mblk = L / 3, nblk = L - mblk * 3;

    auto stage = [&](int s, int buf) {
        const char* asrc = attst + (size_t)mblk * 98304 + s * 16384 + wid * 4096 + lane * 16;
        const char* bsrc = wos   + (size_t)nblk * 98304 + s * 16384 + wid * 4096 + lane * 16;
        char* adst = smem + buf * 16384 + wid * 4096;
        char* bdst = smem + 32768 + buf * 16384 + wid * 4096;
        #pragma unroll
        for (int j = 0; j < 4; ++j) {
            gload16(asrc + j * 1024, adst + j * 1024);
            gload16(bsrc + j * 1024, bdst + j * 1024);
        }
    };

    f32x4 acc[4][4] = {};
    auto compute = [&](int buf) {
        const char* ab = smem + buf * 16384;
        const char* bbp = smem + 32768 + buf * 16384;
        #pragma unroll
        for (int c = 0; c < 2; ++c) {
            const int sw = ((c * 4 + g) ^ (r16 & 7)) << 4;
            short8 a[4], bf[4];
            #pragma unroll
            for (int mi = 0; mi < 4; ++mi)
                a[mi] = *(const short8*)(ab + (wm * 64 + mi * 16 + r16) * 128 + sw);
            #pragma unroll
            for (int ni = 0; ni < 4; ++ni)
                bf[ni] = *(const short8*)(bbp + (wn * 64 + ni * 16 + r16) * 128 + sw);
            #pragma unroll
            for (int mi = 0; mi < 4; ++mi)
                #pragma unroll
                for (int ni = 0; ni < 4; ++ni)
                    acc[mi][ni] = MFMA16(a[mi], bf[ni], acc[mi][ni]);
        }
    };

    stage(0, 0);
    for (int s = 0; s < 6; ++s) {
        __syncthreads();
        if (s < 5) stage(s + 1, (s + 1) & 1);
        compute(s & 1);
    }

    float bias[4];
    #pragma unroll
    for (int ni = 0; ni < 4; ++ni) bias[ni] = b_out[nblk * 128 + wn * 64 + ni * 16 + r16];

    #pragma unroll
    for (int mi = 0; mi < 4; ++mi) {
        #pragma unroll
        for (int r = 0; r < 4; ++r) {
            int T = mblk * 128 + wm * 64 + mi * 16 + g * 4 + r;
            int win = T >> 4, tt = T & 15;
            int bb = win >> 8, wh = (win >> 4) & 15, ww = win & 15;
            size_t o = ((size_t)bb * 4096 + (wh * 4 + (tt >> 2)) * 64 + ww * 4 + (tt & 3)) * 384
                     + nblk * 128 + wn * 64;
            #pragma unroll
            for (int ni = 0; ni < 4; ++ni)
                out[o + ni * 16 + r16] = acc[mi][ni][r] + bias[ni];
        }
    }
}

extern "C" void kernel_launch(void* const* d_in, const int* in_sizes, int n_in,
                              void* d_out, int out_size, void* d_ws, size_t ws_size,
                              hipStream_t stream) {
    const float* x     = (const float*)d_in[0];
    const float* w_in  = (const float*)d_in[1];
    const float* b_in  = (const float*)d_in[2];
    const float* w_out = (const float*)d_in[3];
    const float* b_out = (const float*)d_in[4];
    float* out = (float*)d_out;

    char* ws = (char*)d_ws;
    char*  wst = ws + kWstOff;
    char*  wos = ws + kWosOff;
    float* brr = (float*)(ws + kBrrOff);
    char*  att = ws + kAttOff;
    // xbf scratch lives in d_out: written by prep_x, consumed by qkv_attn,
    // then fully overwritten by out_proj (stream-ordered, deterministic).
    char*  xbf = (char*)d_out;

    prep<<<dim3(288), dim3(256), 0, stream>>>(w_in, b_in, w_out, wst, wos, brr);
    prep_x<<<dim3(24576), dim3(256), 0, stream>>>(x, xbf);
    qkv_attn<<<dim3(12288), dim3(256), 0, stream>>>(xbf, wst, brr, att);
    out_proj<<<dim3(3072), dim3(256), 0, stream>>>(att, wos, b_out, out);
}